// Round 8
// baseline (2073.231 us; speedup 1.0000x reference)
//
#include <hip/hip_runtime.h>
#include <math.h>

#define NN 50000
#define NE 600000
#define NG 512

typedef unsigned int u32;
typedef unsigned short u16;

__device__ __forceinline__ float bf2f(u16 u) {
  return __uint_as_float(((u32)u) << 16);
}
__device__ __forceinline__ u16 f2bf(float f) {
  u32 u = __float_as_uint(f);
  u32 lsb = (u >> 16) & 1u;
  u += 0x7fffu + lsb;          // RNE
  return (u16)(u >> 16);
}

// ================= CSR build (once per launch) ========
__global__ __launch_bounds__(256)
void deg_count_k(const int* __restrict__ ei, int* __restrict__ deg) {
  int e = blockIdx.x * 256 + threadIdx.x;
  if (e >= NE) return;
  atomicAdd(&deg[ei[NE + e]], 1);
}

__global__ __launch_bounds__(1024)
void scan_k(const int* __restrict__ deg, int* __restrict__ row_ptr, int* __restrict__ cursor) {
  __shared__ int sums[1024];
  const int CH = 49;                 // 1024*49 = 50176 >= 50000
  int t = threadIdx.x;
  int base = t * CH;
  int s = 0;
  for (int i = 0; i < CH; i++) { int idx = base + i; if (idx < NN) s += deg[idx]; }
  sums[t] = s;
  __syncthreads();
  for (int off = 1; off < 1024; off <<= 1) {
    int v = (t >= off) ? sums[t - off] : 0;
    __syncthreads();
    sums[t] += v;
    __syncthreads();
  }
  int prefix = (t == 0) ? 0 : sums[t - 1];
  for (int i = 0; i < CH; i++) {
    int idx = base + i;
    if (idx < NN) { row_ptr[idx] = prefix; cursor[idx] = prefix; prefix += deg[idx]; }
  }
  if (t == 1023) row_ptr[NN] = sums[1023];
}

__global__ __launch_bounds__(256)
void fill_k(const int* __restrict__ ei, int* __restrict__ cursor, int* __restrict__ perm) {
  int e = blockIdx.x * 256 + threadIdx.x;
  if (e >= NE) return;
  int pos = atomicAdd(&cursor[ei[NE + e]], 1);
  perm[pos] = ei[e];
}

// ================= cast x (f32) -> xb (bf16) =================
__global__ __launch_bounds__(256)
void cast_k(const float* __restrict__ x, u32* __restrict__ xb) {
  int tid = blockIdx.x * 256 + threadIdx.x;       // 12500*256 = 3,200,000 exactly
  float2 v = ((const float2*)x)[tid];
  xb[tid] = (u32)f2bf(v.x) | ((u32)f2bf(v.y) << 16);
}

// ===== gather-mean from bf16 features: agg[n] = mean_{e in(n)} xb[perm[e]] (f32 out) =====
// one wave per node; lane owns channels (2*lane, 2*lane+1) = one u32.
// Full batches of 8 independent loads (index clamped, accumulate predicated).
__global__ __launch_bounds__(256)
void gather_bf_k(const u16* __restrict__ xb, const int* __restrict__ row_ptr,
                 const int* __restrict__ perm, float* __restrict__ agg) {
  int wave = threadIdx.x >> 6;
  int lane = threadIdx.x & 63;
  int n = blockIdx.x * 4 + wave;          // 12500 * 4 = 50000
  int beg = row_ptr[n], end = row_ptr[n + 1];
  int cnt = end - beg;
  int co = lane * 2;
  float ax[8], ay[8];
#pragma unroll
  for (int j = 0; j < 8; j++) { ax[j] = 0.f; ay[j] = 0.f; }
  for (int base = 0; base < cnt; base += 8) {
    int rem = cnt - base;                 // wave-uniform, >0
    int last = rem - 1;
    int idx[8];
#pragma unroll
    for (int j = 0; j < 8; j++) idx[j] = perm[beg + base + min(j, last)];
    u32 u[8];
#pragma unroll
    for (int j = 0; j < 8; j++) u[j] = *(const u32*)(xb + (size_t)idx[j] * 128 + co);
#pragma unroll
    for (int j = 0; j < 8; j++) {
      bool live = j < rem;
      ax[j] += live ? __uint_as_float(u[j] << 16) : 0.f;
      ay[j] += live ? __uint_as_float(u[j] & 0xffff0000u) : 0.f;
    }
  }
  float sx = (ax[0]+ax[1])+(ax[2]+ax[3])+((ax[4]+ax[5])+(ax[6]+ax[7]));
  float sy = (ay[0]+ay[1])+(ay[2]+ay[3])+((ay[4]+ay[5])+(ay[6]+ay[7]));
  float inv = 1.0f / fmaxf((float)cnt, 1.0f);
  float2 o = { sx * inv, sy * inv };
  *(float2*)(agg + (size_t)n * 128 + co) = o;
}

// ===== SAGE layer Cout=128: out = agg@Wl + bl + x@Wr; 16KB W chunks (8 stage passes) =====
// block 256 = 4 waves; wave owns 4 rows; lane owns cols (2*lane, 2*lane+1).
// 16KB LDS -> ~6 blocks/CU (VGPR-limited), vs 29% occupancy at 32KB chunks (R6).
__global__ __launch_bounds__(256, 5)
void sage128_k(const float* __restrict__ x, const float* __restrict__ agg,
               const float* __restrict__ Wl, const float* __restrict__ bl,
               const float* __restrict__ Wr,
               float* __restrict__ out_relu, float* __restrict__ out_pre,
               u16* __restrict__ xb_out, int write_pre, int write_relu_f32) {
  __shared__ __align__(16) float sW[32 * 128];    // 16 KB chunk
  int wave = threadIdx.x >> 6;
  int lane = threadIdx.x & 63;
  int r0 = blockIdx.x * 16 + wave * 4;            // 3125 * 16 = 50000
  int co = lane * 2;

  float acc0[4] = {0.f, 0.f, 0.f, 0.f};
  float acc1[4] = {0.f, 0.f, 0.f, 0.f};

  for (int half = 0; half < 8; half++) {
    const float* Wg = (half < 4) ? Wl : Wr;
    const float* src = (half < 4) ? agg : x;
    int kbase = (half & 3) * 32;
    __syncthreads();
    {
      const float4* g = (const float4*)(Wg + kbase * 128);
      float4* s = (float4*)sW;
      for (int t = threadIdx.x; t < 1024; t += 256) s[t] = g[t];
    }
    __syncthreads();
    for (int kb = 0; kb < 4; kb++) {
      int k0 = kb * 8;
      int kk = kbase + k0;
      float w0[8], w1[8];
#pragma unroll
      for (int j = 0; j < 8; j++) {
        float2 wp = *(const float2*)(&sW[(k0 + j) * 128 + co]);
        w0[j] = wp.x; w1[j] = wp.y;
      }
#pragma unroll
      for (int i = 0; i < 4; i++) {
        float4 a0 = *(const float4*)(src + (size_t)(r0 + i) * 128 + kk);
        float4 a1 = *(const float4*)(src + (size_t)(r0 + i) * 128 + kk + 4);
        float vin[8] = {a0.x, a0.y, a0.z, a0.w, a1.x, a1.y, a1.z, a1.w};
#pragma unroll
        for (int j = 0; j < 8; j++) {
          acc0[i] = fmaf(vin[j], w0[j], acc0[i]);
          acc1[i] = fmaf(vin[j], w1[j], acc1[i]);
        }
      }
    }
  }
  float2 bp = *(const float2*)(bl + co);
#pragma unroll
  for (int i = 0; i < 4; i++) {
    int r = r0 + i;
    float v0 = acc0[i] + bp.x;
    float v1 = acc1[i] + bp.y;
    if (write_pre) {
      float2 p = {v0, v1};
      *(float2*)(out_pre + (size_t)r * 128 + co) = p;
    }
    float r0f = fmaxf(v0, 0.0f), r1f = fmaxf(v1, 0.0f);
    if (write_relu_f32) {
      float2 q = {r0f, r1f};
      *(float2*)(out_relu + (size_t)r * 128 + co) = q;
    }
    *(u32*)(xb_out + (size_t)r * 128 + co) = (u32)f2bf(r0f) | ((u32)f2bf(r1f) << 16);
  }
}

// ===== final layer Cout=64 + log_softmax; 16KB W chunks; agg f32 + x bf16 global reads =====
__global__ __launch_bounds__(256, 4)
void sage64_k(const u16* __restrict__ xb, const float* __restrict__ agg,
              const float* __restrict__ Wl, const float* __restrict__ bl,
              const float* __restrict__ Wr,
              float* __restrict__ out) {
  __shared__ __align__(16) float sW[64 * 64];     // 16 KB chunk
  int wave = threadIdx.x >> 6;
  int lane = threadIdx.x & 63;
  int r0 = blockIdx.x * 16 + wave * 4;

  float acc[4] = {0.f, 0.f, 0.f, 0.f};

  for (int half = 0; half < 4; half++) {
    const float* Wg = (half < 2) ? Wl : Wr;
    int kbase = (half & 1) * 64;
    int useAgg = (half < 2);
    __syncthreads();
    {
      const float4* g = (const float4*)(Wg + kbase * 64);
      float4* s = (float4*)sW;
      for (int t = threadIdx.x; t < 1024; t += 256) s[t] = g[t];
    }
    __syncthreads();
    for (int kb = 0; kb < 8; kb++) {
      int k0 = kb * 8;
      int kk = kbase + k0;
      float w[8];
#pragma unroll
      for (int j = 0; j < 8; j++) w[j] = sW[(k0 + j) * 64 + lane];
#pragma unroll
      for (int i = 0; i < 4; i++) {
        float vin[8];
        if (useAgg) {
          float4 a0 = *(const float4*)(agg + (size_t)(r0 + i) * 128 + kk);
          float4 a1 = *(const float4*)(agg + (size_t)(r0 + i) * 128 + kk + 4);
          vin[0] = a0.x; vin[1] = a0.y; vin[2] = a0.z; vin[3] = a0.w;
          vin[4] = a1.x; vin[5] = a1.y; vin[6] = a1.z; vin[7] = a1.w;
        } else {
          uint4 xv = *(const uint4*)(xb + (size_t)(r0 + i) * 128 + kk);
          vin[0] = __uint_as_float(xv.x << 16); vin[1] = __uint_as_float(xv.x & 0xffff0000u);
          vin[2] = __uint_as_float(xv.y << 16); vin[3] = __uint_as_float(xv.y & 0xffff0000u);
          vin[4] = __uint_as_float(xv.z << 16); vin[5] = __uint_as_float(xv.z & 0xffff0000u);
          vin[6] = __uint_as_float(xv.w << 16); vin[7] = __uint_as_float(xv.w & 0xffff0000u);
        }
#pragma unroll
        for (int j = 0; j < 8; j++) acc[i] = fmaf(vin[j], w[j], acc[i]);
      }
    }
  }
  float b = bl[lane];
#pragma unroll
  for (int i = 0; i < 4; i++) {
    float v = acc[i] + b;
    float m = v;
#pragma unroll
    for (int off = 32; off > 0; off >>= 1) m = fmaxf(m, __shfl_xor(m, off));
    float e = __expf(v - m);
    float s = e;
#pragma unroll
    for (int off = 32; off > 0; off >>= 1) s += __shfl_xor(s, off);
    float ls = v - m - __logf(s);
    out[(size_t)(r0 + i) * 64 + lane] = ls;
  }
}

// ======= graph pooling from bf16 x2 (cluster sorted -> segmented mean, no atomics) =======
__global__ __launch_bounds__(128)
void pool_seg_k(const u16* __restrict__ xb, const int* __restrict__ cluster,
                float* __restrict__ g) {
  int gid = blockIdx.x;          // 512
  int ch = threadIdx.x;          // 128
  int lo = 0, hi = NN;
  while (lo < hi) { int mid = (lo + hi) >> 1; if (cluster[mid] < gid) lo = mid + 1; else hi = mid; }
  int beg = lo;
  hi = NN;
  while (lo < hi) { int mid = (lo + hi) >> 1; if (cluster[mid] < gid + 1) lo = mid + 1; else hi = mid; }
  int end = lo;
  float s0 = 0.f, s1 = 0.f, s2 = 0.f, s3 = 0.f;
  int n = beg;
  for (; n + 4 <= end; n += 4) {
    s0 += bf2f(xb[(size_t)(n + 0) * 128 + ch]);
    s1 += bf2f(xb[(size_t)(n + 1) * 128 + ch]);
    s2 += bf2f(xb[(size_t)(n + 2) * 128 + ch]);
    s3 += bf2f(xb[(size_t)(n + 3) * 128 + ch]);
  }
  for (; n < end; n++) s0 += bf2f(xb[(size_t)n * 128 + ch]);
  float s = (s0 + s1) + (s2 + s3);
  g[gid * 128 + ch] = s / fmaxf((float)(end - beg), 1.0f);
}

extern "C" void kernel_launch(void* const* d_in, const int* in_sizes, int n_in,
                              void* d_out, int out_size, void* d_ws, size_t ws_size,
                              hipStream_t stream) {
  const float* x   = (const float*)d_in[0];
  const int*   ei  = (const int*)d_in[1];
  const int*   cl  = (const int*)d_in[2];
  const float* Wl0 = (const float*)d_in[3];
  const float* bl0 = (const float*)d_in[4];
  const float* Wr0 = (const float*)d_in[5];
  const float* Wl1 = (const float*)d_in[6];
  const float* bl1 = (const float*)d_in[7];
  const float* Wr1 = (const float*)d_in[8];
  const float* Wl2 = (const float*)d_in[9];
  const float* bl2 = (const float*)d_in[10];
  const float* Wr2 = (const float*)d_in[11];
  float* out = (float*)d_out;

  char* ws = (char*)d_ws;
  float* x1      = (float*)(ws);                  // 25,600,000 B (f32 relu of layer0)
  float* agg     = (float*)(ws + 25600000);       // 25,600,000 B
  u16*   xb      = (u16*)  (ws + 51200000);       // 12,800,000 B (bf16 mirror, reused per layer)
  int*   deg     = (int*)  (ws + 64000000);       //    200,000 B
  int*   row_ptr = (int*)  (ws + 64200192);       //    200,004 B (+pad)
  int*   cursor  = (int*)  (ws + 64400896);       //    200,000 B
  int*   perm    = (int*)  (ws + 64600896);       //  2,400,000 B

  float* out_lsm = out;            // [50000,64]
  float* out_pre = out + 3200000;  // [50000,128]
  float* out_g   = out + 9600000;  // [512,128]

  // ---- CSR build (once) ----
  hipMemsetAsync(deg, 0, 200000, stream);
  deg_count_k<<<2344, 256, 0, stream>>>(ei, deg);
  scan_k<<<1, 1024, 0, stream>>>(deg, row_ptr, cursor);
  fill_k<<<2344, 256, 0, stream>>>(ei, cursor, perm);

  // ---- layer 0 ----
  cast_k<<<12500, 256, 0, stream>>>(x, (u32*)xb);
  gather_bf_k<<<12500, 256, 0, stream>>>(xb, row_ptr, perm, agg);
  sage128_k<<<3125, 256, 0, stream>>>(x, agg, Wl0, bl0, Wr0, x1, nullptr, xb, 0, 1);

  // ---- layer 1 (pre-relu f32 straight to d_out; relu only as bf16 mirror) ----
  gather_bf_k<<<12500, 256, 0, stream>>>(xb, row_ptr, perm, agg);
  sage128_k<<<3125, 256, 0, stream>>>(x1, agg, Wl1, bl1, Wr1, nullptr, out_pre, xb, 1, 0);

  // ---- graph pooling of x2 (bf16) ----
  pool_seg_k<<<NG, 128, 0, stream>>>(xb, cl, out_g);

  // ---- final layer + log_softmax ----
  gather_bf_k<<<12500, 256, 0, stream>>>(xb, row_ptr, perm, agg);
  sage64_k<<<3125, 256, 0, stream>>>(xb, agg, Wl2, bl2, Wr2, out_lsm);
}

// Round 9
// 711.418 us; speedup vs baseline: 2.9142x; 2.9142x over previous
//
#include <hip/hip_runtime.h>
#include <math.h>

#define NN 50000
#define NE 600000
#define NG 512

typedef unsigned int u32;
typedef unsigned short u16;

__device__ __forceinline__ float bf2f(u16 u) {
  return __uint_as_float(((u32)u) << 16);
}
__device__ __forceinline__ u16 f2bf(float f) {
  u32 u = __float_as_uint(f);
  u32 lsb = (u >> 16) & 1u;
  u += 0x7fffu + lsb;          // RNE
  return (u16)(u >> 16);
}

// ================= CSR build (once per launch) ========
__global__ __launch_bounds__(256)
void deg_count_k(const int* __restrict__ ei, int* __restrict__ deg) {
  int e = blockIdx.x * 256 + threadIdx.x;
  if (e >= NE) return;
  atomicAdd(&deg[ei[NE + e]], 1);
}

__global__ __launch_bounds__(1024)
void scan_k(const int* __restrict__ deg, int* __restrict__ row_ptr, int* __restrict__ cursor) {
  __shared__ int sums[1024];
  const int CH = 49;                 // 1024*49 = 50176 >= 50000
  int t = threadIdx.x;
  int base = t * CH;
  int s = 0;
  for (int i = 0; i < CH; i++) { int idx = base + i; if (idx < NN) s += deg[idx]; }
  sums[t] = s;
  __syncthreads();
  for (int off = 1; off < 1024; off <<= 1) {
    int v = (t >= off) ? sums[t - off] : 0;
    __syncthreads();
    sums[t] += v;
    __syncthreads();
  }
  int prefix = (t == 0) ? 0 : sums[t - 1];
  for (int i = 0; i < CH; i++) {
    int idx = base + i;
    if (idx < NN) { row_ptr[idx] = prefix; cursor[idx] = prefix; prefix += deg[idx]; }
  }
  if (t == 1023) row_ptr[NN] = sums[1023];
}

__global__ __launch_bounds__(256)
void fill_k(const int* __restrict__ ei, int* __restrict__ cursor, int* __restrict__ perm) {
  int e = blockIdx.x * 256 + threadIdx.x;
  if (e >= NE) return;
  int pos = atomicAdd(&cursor[ei[NE + e]], 1);
  perm[pos] = ei[e];
}

// ================= cast x (f32) -> xb (bf16) =================
__global__ __launch_bounds__(256)
void cast_k(const float* __restrict__ x, u32* __restrict__ xb) {
  int tid = blockIdx.x * 256 + threadIdx.x;       // 12500*256 = 3,200,000 exactly
  float2 v = ((const float2*)x)[tid];
  xb[tid] = (u32)f2bf(v.x) | ((u32)f2bf(v.y) << 16);
}

// ===== gather-mean from bf16 features: agg[n] = mean_{e in(n)} xb[perm[e]] (f32 out) =====
// one wave per node; lane owns channels (2*lane, 2*lane+1) = one u32.
// Full batches of 8 independent loads (index clamped, accumulate predicated).
__global__ __launch_bounds__(256)
void gather_bf_k(const u16* __restrict__ xb, const int* __restrict__ row_ptr,
                 const int* __restrict__ perm, float* __restrict__ agg) {
  int wave = threadIdx.x >> 6;
  int lane = threadIdx.x & 63;
  int n = blockIdx.x * 4 + wave;          // 12500 * 4 = 50000
  int beg = row_ptr[n], end = row_ptr[n + 1];
  int cnt = end - beg;
  int co = lane * 2;
  float ax[8], ay[8];
#pragma unroll
  for (int j = 0; j < 8; j++) { ax[j] = 0.f; ay[j] = 0.f; }
  for (int base = 0; base < cnt; base += 8) {
    int rem = cnt - base;                 // wave-uniform, >0
    int last = rem - 1;
    int idx[8];
#pragma unroll
    for (int j = 0; j < 8; j++) idx[j] = perm[beg + base + min(j, last)];
    u32 u[8];
#pragma unroll
    for (int j = 0; j < 8; j++) u[j] = *(const u32*)(xb + (size_t)idx[j] * 128 + co);
#pragma unroll
    for (int j = 0; j < 8; j++) {
      bool live = j < rem;
      ax[j] += live ? __uint_as_float(u[j] << 16) : 0.f;
      ay[j] += live ? __uint_as_float(u[j] & 0xffff0000u) : 0.f;
    }
  }
  float sx = (ax[0]+ax[1])+(ax[2]+ax[3])+((ax[4]+ax[5])+(ax[6]+ax[7]));
  float sy = (ay[0]+ay[1])+(ay[2]+ay[3])+((ay[4]+ay[5])+(ay[6]+ay[7]));
  float inv = 1.0f / fmaxf((float)cnt, 1.0f);
  float2 o = { sx * inv, sy * inv };
  *(float2*)(agg + (size_t)n * 128 + co) = o;
}

// ===== SAGE layer Cout=128: out = agg@Wl + bl + x@Wr; 32KB W chunks (4 stage passes) =====
// block 256 = 4 waves; wave owns EIGHT rows (2x R6: doubles FMA chains + in-flight loads);
// lane owns cols (2*lane, 2*lane+1). 1563 blocks * 32 rows >= 50000 (guarded tail).
template<bool WRITE_PRE, bool WRITE_RELU_F32>
__global__ __launch_bounds__(256)
void sage128_k(const float* __restrict__ x, const float* __restrict__ agg,
               const float* __restrict__ Wl, const float* __restrict__ bl,
               const float* __restrict__ Wr,
               float* __restrict__ out_relu, float* __restrict__ out_pre,
               u16* __restrict__ xb_out) {
  __shared__ __align__(16) float sW[64 * 128];    // 32 KB chunk
  int wave = threadIdx.x >> 6;
  int lane = threadIdx.x & 63;
  int r0 = blockIdx.x * 32 + wave * 8;
  int co = lane * 2;

  float acc0[8], acc1[8];
#pragma unroll
  for (int i = 0; i < 8; i++) { acc0[i] = 0.f; acc1[i] = 0.f; }

  for (int half = 0; half < 4; half++) {
    const float* Wg = (half < 2) ? Wl : Wr;
    const float* src = (half < 2) ? agg : x;
    int kbase = (half & 1) * 64;
    __syncthreads();
    {
      const float4* g = (const float4*)(Wg + kbase * 128);
      float4* s = (float4*)sW;
      for (int t = threadIdx.x; t < 2048; t += 256) s[t] = g[t];
    }
    __syncthreads();
    for (int kb = 0; kb < 8; kb++) {
      int k0 = kb * 8;
      int kk = kbase + k0;
      float w0[8], w1[8];
#pragma unroll
      for (int j = 0; j < 8; j++) {
        float2 wp = *(const float2*)(&sW[(k0 + j) * 128 + co]);
        w0[j] = wp.x; w1[j] = wp.y;
      }
#pragma unroll
      for (int i = 0; i < 8; i++) {
        int r = min(r0 + i, NN - 1);      // wave-uniform clamp (scalar ops)
        float4 a0 = *(const float4*)(src + (size_t)r * 128 + kk);
        float4 a1 = *(const float4*)(src + (size_t)r * 128 + kk + 4);
        float vin[8] = {a0.x, a0.y, a0.z, a0.w, a1.x, a1.y, a1.z, a1.w};
#pragma unroll
        for (int j = 0; j < 8; j++) {
          acc0[i] = fmaf(vin[j], w0[j], acc0[i]);
          acc1[i] = fmaf(vin[j], w1[j], acc1[i]);
        }
      }
    }
  }
  float2 bp = *(const float2*)(bl + co);
#pragma unroll
  for (int i = 0; i < 8; i++) {
    int r = r0 + i;
    if (r < NN) {
      float v0 = acc0[i] + bp.x;
      float v1 = acc1[i] + bp.y;
      if (WRITE_PRE) {
        float2 p = {v0, v1};
        *(float2*)(out_pre + (size_t)r * 128 + co) = p;
      }
      float r0f = fmaxf(v0, 0.0f), r1f = fmaxf(v1, 0.0f);
      if (WRITE_RELU_F32) {
        float2 q = {r0f, r1f};
        *(float2*)(out_relu + (size_t)r * 128 + co) = q;
      }
      *(u32*)(xb_out + (size_t)r * 128 + co) = (u32)f2bf(r0f) | ((u32)f2bf(r1f) << 16);
    }
  }
}

// ===== final layer Cout=64 + log_softmax; R6-exact (32KB W per pass, 2 passes) =====
__global__ __launch_bounds__(256)
void sage64_k(const u16* __restrict__ xb, const float* __restrict__ agg,
              const float* __restrict__ Wl, const float* __restrict__ bl,
              const float* __restrict__ Wr,
              float* __restrict__ out) {
  __shared__ __align__(16) float sW[128 * 64];    // 32 KB (one full W per pass)
  int wave = threadIdx.x >> 6;
  int lane = threadIdx.x & 63;
  int r0 = blockIdx.x * 16 + wave * 4;

  float acc[4] = {0.f, 0.f, 0.f, 0.f};

  for (int pass = 0; pass < 2; pass++) {
    const float* Wg = pass ? Wr : Wl;
    __syncthreads();
    {
      const float4* g = (const float4*)Wg;
      float4* s = (float4*)sW;
      for (int t = threadIdx.x; t < 2048; t += 256) s[t] = g[t];
    }
    __syncthreads();
    for (int kb = 0; kb < 16; kb++) {
      int k0 = kb * 8;
      float w[8];
#pragma unroll
      for (int j = 0; j < 8; j++) w[j] = sW[(k0 + j) * 64 + lane];
#pragma unroll
      for (int i = 0; i < 4; i++) {
        float vin[8];
        if (pass == 0) {
          float4 a0 = *(const float4*)(agg + (size_t)(r0 + i) * 128 + k0);
          float4 a1 = *(const float4*)(agg + (size_t)(r0 + i) * 128 + k0 + 4);
          vin[0] = a0.x; vin[1] = a0.y; vin[2] = a0.z; vin[3] = a0.w;
          vin[4] = a1.x; vin[5] = a1.y; vin[6] = a1.z; vin[7] = a1.w;
        } else {
          uint4 xv = *(const uint4*)(xb + (size_t)(r0 + i) * 128 + k0);
          vin[0] = __uint_as_float(xv.x << 16); vin[1] = __uint_as_float(xv.x & 0xffff0000u);
          vin[2] = __uint_as_float(xv.y << 16); vin[3] = __uint_as_float(xv.y & 0xffff0000u);
          vin[4] = __uint_as_float(xv.z << 16); vin[5] = __uint_as_float(xv.z & 0xffff0000u);
          vin[6] = __uint_as_float(xv.w << 16); vin[7] = __uint_as_float(xv.w & 0xffff0000u);
        }
#pragma unroll
        for (int j = 0; j < 8; j++) acc[i] = fmaf(vin[j], w[j], acc[i]);
      }
    }
  }
  float b = bl[lane];
#pragma unroll
  for (int i = 0; i < 4; i++) {
    float v = acc[i] + b;
    float m = v;
#pragma unroll
    for (int off = 32; off > 0; off >>= 1) m = fmaxf(m, __shfl_xor(m, off));
    float e = __expf(v - m);
    float s = e;
#pragma unroll
    for (int off = 32; off > 0; off >>= 1) s += __shfl_xor(s, off);
    float ls = v - m - __logf(s);
    out[(size_t)(r0 + i) * 64 + lane] = ls;
  }
}

// ======= graph pooling from bf16 x2 (cluster sorted -> segmented mean, no atomics) =======
__global__ __launch_bounds__(128)
void pool_seg_k(const u16* __restrict__ xb, const int* __restrict__ cluster,
                float* __restrict__ g) {
  int gid = blockIdx.x;          // 512
  int ch = threadIdx.x;          // 128
  int lo = 0, hi = NN;
  while (lo < hi) { int mid = (lo + hi) >> 1; if (cluster[mid] < gid) lo = mid + 1; else hi = mid; }
  int beg = lo;
  hi = NN;
  while (lo < hi) { int mid = (lo + hi) >> 1; if (cluster[mid] < gid + 1) lo = mid + 1; else hi = mid; }
  int end = lo;
  float s0 = 0.f, s1 = 0.f, s2 = 0.f, s3 = 0.f;
  int n = beg;
  for (; n + 4 <= end; n += 4) {
    s0 += bf2f(xb[(size_t)(n + 0) * 128 + ch]);
    s1 += bf2f(xb[(size_t)(n + 1) * 128 + ch]);
    s2 += bf2f(xb[(size_t)(n + 2) * 128 + ch]);
    s3 += bf2f(xb[(size_t)(n + 3) * 128 + ch]);
  }
  for (; n < end; n++) s0 += bf2f(xb[(size_t)n * 128 + ch]);
  float s = (s0 + s1) + (s2 + s3);
  g[gid * 128 + ch] = s / fmaxf((float)(end - beg), 1.0f);
}

extern "C" void kernel_launch(void* const* d_in, const int* in_sizes, int n_in,
                              void* d_out, int out_size, void* d_ws, size_t ws_size,
                              hipStream_t stream) {
  const float* x   = (const float*)d_in[0];
  const int*   ei  = (const int*)d_in[1];
  const int*   cl  = (const int*)d_in[2];
  const float* Wl0 = (const float*)d_in[3];
  const float* bl0 = (const float*)d_in[4];
  const float* Wr0 = (const float*)d_in[5];
  const float* Wl1 = (const float*)d_in[6];
  const float* bl1 = (const float*)d_in[7];
  const float* Wr1 = (const float*)d_in[8];
  const float* Wl2 = (const float*)d_in[9];
  const float* bl2 = (const float*)d_in[10];
  const float* Wr2 = (const float*)d_in[11];
  float* out = (float*)d_out;

  char* ws = (char*)d_ws;
  float* x1      = (float*)(ws);                  // 25,600,000 B (f32 relu of layer0)
  float* agg     = (float*)(ws + 25600000);       // 25,600,000 B
  u16*   xb      = (u16*)  (ws + 51200000);       // 12,800,000 B (bf16 mirror, reused per layer)
  int*   deg     = (int*)  (ws + 64000000);       //    200,000 B
  int*   row_ptr = (int*)  (ws + 64200192);       //    200,004 B (+pad)
  int*   cursor  = (int*)  (ws + 64400896);       //    200,000 B
  int*   perm    = (int*)  (ws + 64600896);       //  2,400,000 B

  float* out_lsm = out;            // [50000,64]
  float* out_pre = out + 3200000;  // [50000,128]
  float* out_g   = out + 9600000;  // [512,128]

  // ---- CSR build (once) ----
  hipMemsetAsync(deg, 0, 200000, stream);
  deg_count_k<<<2344, 256, 0, stream>>>(ei, deg);
  scan_k<<<1, 1024, 0, stream>>>(deg, row_ptr, cursor);
  fill_k<<<2344, 256, 0, stream>>>(ei, cursor, perm);

  // ---- layer 0 ----
  cast_k<<<12500, 256, 0, stream>>>(x, (u32*)xb);
  gather_bf_k<<<12500, 256, 0, stream>>>(xb, row_ptr, perm, agg);
  sage128_k<false, true><<<1563, 256, 0, stream>>>(x, agg, Wl0, bl0, Wr0, x1, nullptr, xb);

  // ---- layer 1 (pre-relu f32 straight to d_out; relu only as bf16 mirror) ----
  gather_bf_k<<<12500, 256, 0, stream>>>(xb, row_ptr, perm, agg);
  sage128_k<true, false><<<1563, 256, 0, stream>>>(x1, agg, Wl1, bl1, Wr1, nullptr, out_pre, xb);

  // ---- graph pooling of x2 (bf16) ----
  pool_seg_k<<<NG, 128, 0, stream>>>(xb, cl, out_g);

  // ---- final layer + log_softmax ----
  gather_bf_k<<<12500, 256, 0, stream>>>(xb, row_ptr, perm, agg);
  sage64_k<<<3125, 256, 0, stream>>>(xb, agg, Wl2, bl2, Wr2, out_lsm);
}

// Round 10
// 513.470 us; speedup vs baseline: 4.0377x; 1.3855x over previous
//
#include <hip/hip_runtime.h>
#include <math.h>

#define NN 50000
#define NE 600000
#define NG 512

typedef unsigned int u32;
typedef unsigned short u16;

typedef __attribute__((ext_vector_type(8))) short bf16x8;
typedef __attribute__((ext_vector_type(4))) float f32x4;

__device__ __forceinline__ float bf2f(u16 u) {
  return __uint_as_float(((u32)u) << 16);
}
__device__ __forceinline__ u16 f2bf(float f) {
  u32 u = __float_as_uint(f);
  u32 lsb = (u >> 16) & 1u;
  u += 0x7fffu + lsb;          // RNE
  return (u16)(u >> 16);
}

// ================= CSR build (once per launch) ========
__global__ __launch_bounds__(256)
void deg_count_k(const int* __restrict__ ei, int* __restrict__ deg) {
  int e = blockIdx.x * 256 + threadIdx.x;
  if (e >= NE) return;
  atomicAdd(&deg[ei[NE + e]], 1);
}

__global__ __launch_bounds__(1024)
void scan_k(const int* __restrict__ deg, int* __restrict__ row_ptr, int* __restrict__ cursor) {
  __shared__ int sums[1024];
  const int CH = 49;                 // 1024*49 = 50176 >= 50000
  int t = threadIdx.x;
  int base = t * CH;
  int s = 0;
  for (int i = 0; i < CH; i++) { int idx = base + i; if (idx < NN) s += deg[idx]; }
  sums[t] = s;
  __syncthreads();
  for (int off = 1; off < 1024; off <<= 1) {
    int v = (t >= off) ? sums[t - off] : 0;
    __syncthreads();
    sums[t] += v;
    __syncthreads();
  }
  int prefix = (t == 0) ? 0 : sums[t - 1];
  for (int i = 0; i < CH; i++) {
    int idx = base + i;
    if (idx < NN) { row_ptr[idx] = prefix; cursor[idx] = prefix; prefix += deg[idx]; }
  }
  if (t == 1023) row_ptr[NN] = sums[1023];
}

__global__ __launch_bounds__(256)
void fill_k(const int* __restrict__ ei, int* __restrict__ cursor, int* __restrict__ perm) {
  int e = blockIdx.x * 256 + threadIdx.x;
  if (e >= NE) return;
  int pos = atomicAdd(&cursor[ei[NE + e]], 1);
  perm[pos] = ei[e];
}

// ================= cast x (f32) -> xb (bf16) =================
__global__ __launch_bounds__(256)
void cast_k(const float* __restrict__ x, u32* __restrict__ xb) {
  int tid = blockIdx.x * 256 + threadIdx.x;       // 12500*256 = 3,200,000 exactly
  float2 v = ((const float2*)x)[tid];
  xb[tid] = (u32)f2bf(v.x) | ((u32)f2bf(v.y) << 16);
}

// ===== weight cast+transpose: WbT[n][k] = bf16( k<128 ? Wl[k][n] : Wr[k-128][n] ) =====
__global__ __launch_bounds__(256)
void castW_k(const float* __restrict__ Wl, const float* __restrict__ Wr,
             u16* __restrict__ WbT, int ncols) {   // ncols = 128 or 64
  int t = blockIdx.x * 256 + threadIdx.x;          // ncols*256 threads
  int n = t >> 8;
  int k = t & 255;
  if (n >= ncols) return;
  float v = (k < 128) ? Wl[k * ncols + n] : Wr[(k - 128) * ncols + n];
  WbT[n * 256 + k] = f2bf(v);
}

// ===== gather-mean (bf16 in, bf16 out): aggb[n] = bf16(mean_{e in(n)} xb[perm[e]]) =====
// one wave per node; lane owns channels (2*lane, 2*lane+1) = one u32.
__global__ __launch_bounds__(256)
void gather_bf_k(const u16* __restrict__ xb, const int* __restrict__ row_ptr,
                 const int* __restrict__ perm, u16* __restrict__ aggb) {
  int wave = threadIdx.x >> 6;
  int lane = threadIdx.x & 63;
  int n = blockIdx.x * 4 + wave;          // 12500 * 4 = 50000
  int beg = row_ptr[n], end = row_ptr[n + 1];
  int cnt = end - beg;
  int co = lane * 2;
  float ax[8], ay[8];
#pragma unroll
  for (int j = 0; j < 8; j++) { ax[j] = 0.f; ay[j] = 0.f; }
  for (int base = 0; base < cnt; base += 8) {
    int rem = cnt - base;                 // wave-uniform, >0
    int last = rem - 1;
    int idx[8];
#pragma unroll
    for (int j = 0; j < 8; j++) idx[j] = perm[beg + base + min(j, last)];
    u32 u[8];
#pragma unroll
    for (int j = 0; j < 8; j++) u[j] = *(const u32*)(xb + (size_t)idx[j] * 128 + co);
#pragma unroll
    for (int j = 0; j < 8; j++) {
      bool live = j < rem;
      ax[j] += live ? __uint_as_float(u[j] << 16) : 0.f;
      ay[j] += live ? __uint_as_float(u[j] & 0xffff0000u) : 0.f;
    }
  }
  float sx = (ax[0]+ax[1])+(ax[2]+ax[3])+((ax[4]+ax[5])+(ax[6]+ax[7]));
  float sy = (ay[0]+ay[1])+(ay[2]+ay[3])+((ay[4]+ay[5])+(ay[6]+ay[7]));
  float inv = 1.0f / fmaxf((float)cnt, 1.0f);
  *(u32*)(aggb + (size_t)n * 128 + co) = (u32)f2bf(sx * inv) | ((u32)f2bf(sy * inv) << 16);
}

// ===== MFMA SAGE layer Cout=128: C = [aggb|xb] @ [Wl;Wr] (K=256, bf16, f32 acc) =====
// block 256 = 4 waves; wave = one 16x16 C tile; block = 16 rows x 64 cols.
// grid = 3125 row-tiles * 2 col-blocks = 6250. No LDS, no barriers.
// A-frag: lane holds A[m=lane&15][k=quad*8+j] -> contiguous 16B load from row.
// B-frag: lane holds B[k=quad*8+j][n=lane&15] -> contiguous 16B load from WbT[n][*].
// C/D: col=lane&15, row=quad*4+reg.
template<bool WRITE_PRE>
__global__ __launch_bounds__(256)
void sage128_mfma_k(const u16* __restrict__ aggb, const u16* __restrict__ xbin,
                    const u16* __restrict__ WbT, const float* __restrict__ bl,
                    u16* __restrict__ xb_out, float* __restrict__ out_pre) {
  int wave = threadIdx.x >> 6;
  int lane = threadIdx.x & 63;
  int quad = lane >> 4;
  int m16  = lane & 15;
  int r0 = (blockIdx.x >> 1) * 16;
  int c0 = (blockIdx.x & 1) * 64 + wave * 16;

  const u16* arow_a = aggb + (size_t)(r0 + m16) * 128 + quad * 8;
  const u16* arow_x = xbin + (size_t)(r0 + m16) * 128 + quad * 8;
  const u16* brow   = WbT  + (size_t)(c0 + m16) * 256 + quad * 8;

  f32x4 acc = {0.f, 0.f, 0.f, 0.f};
#pragma unroll
  for (int ks = 0; ks < 8; ks++) {
    const u16* asrc = (ks < 4) ? arow_a : arow_x;
    bf16x8 a = *(const bf16x8*)(asrc + (ks & 3) * 32);
    bf16x8 b = *(const bf16x8*)(brow + ks * 32);
    acc = __builtin_amdgcn_mfma_f32_16x16x32_bf16(a, b, acc, 0, 0, 0);
  }
  int c = c0 + m16;
  float bv = bl[c];
#pragma unroll
  for (int r = 0; r < 4; r++) {
    int row = r0 + quad * 4 + r;
    float v = acc[r] + bv;
    if (WRITE_PRE) out_pre[(size_t)row * 128 + c] = v;
    xb_out[(size_t)row * 128 + c] = f2bf(fmaxf(v, 0.f));
  }
}

// ===== MFMA final layer Cout=64 + fused log_softmax =====
// block 256 = 4 waves covering 16 rows x 64 cols (full width); grid 3125.
__global__ __launch_bounds__(256)
void sage64_mfma_k(const u16* __restrict__ aggb, const u16* __restrict__ xbin,
                   const u16* __restrict__ WbT, const float* __restrict__ bl,
                   float* __restrict__ out) {
  __shared__ float sC[16][64];
  int wave = threadIdx.x >> 6;
  int lane = threadIdx.x & 63;
  int quad = lane >> 4;
  int m16  = lane & 15;
  int r0 = blockIdx.x * 16;
  int c0 = wave * 16;

  const u16* arow_a = aggb + (size_t)(r0 + m16) * 128 + quad * 8;
  const u16* arow_x = xbin + (size_t)(r0 + m16) * 128 + quad * 8;
  const u16* brow   = WbT  + (size_t)(c0 + m16) * 256 + quad * 8;

  f32x4 acc = {0.f, 0.f, 0.f, 0.f};
#pragma unroll
  for (int ks = 0; ks < 8; ks++) {
    const u16* asrc = (ks < 4) ? arow_a : arow_x;
    bf16x8 a = *(const bf16x8*)(asrc + (ks & 3) * 32);
    bf16x8 b = *(const bf16x8*)(brow + ks * 32);
    acc = __builtin_amdgcn_mfma_f32_16x16x32_bf16(a, b, acc, 0, 0, 0);
  }
  int c = c0 + m16;
  float bv = bl[c];
#pragma unroll
  for (int r = 0; r < 4; r++) sC[quad * 4 + r][c] = acc[r] + bv;
  __syncthreads();
  if (threadIdx.x < 16) {
    int r = threadIdx.x;
    float m = -1e30f;
    for (int j = 0; j < 64; j++) m = fmaxf(m, sC[r][j]);
    float s = 0.f;
    for (int j = 0; j < 64; j++) s += __expf(sC[r][j] - m);
    float ls = __logf(s);
    float* orow = out + (size_t)(r0 + r) * 64;
    for (int j = 0; j < 64; j++) orow[j] = sC[r][j] - m - ls;
  }
}

// ======= graph pooling from bf16 (cluster sorted -> segmented mean, no atomics) =======
__global__ __launch_bounds__(128)
void pool_seg_k(const u16* __restrict__ xb, const int* __restrict__ cluster,
                float* __restrict__ g) {
  int gid = blockIdx.x;          // 512
  int ch = threadIdx.x;          // 128
  int lo = 0, hi = NN;
  while (lo < hi) { int mid = (lo + hi) >> 1; if (cluster[mid] < gid) lo = mid + 1; else hi = mid; }
  int beg = lo;
  hi = NN;
  while (lo < hi) { int mid = (lo + hi) >> 1; if (cluster[mid] < gid + 1) lo = mid + 1; else hi = mid; }
  int end = lo;
  float s0 = 0.f, s1 = 0.f, s2 = 0.f, s3 = 0.f;
  int n = beg;
  for (; n + 4 <= end; n += 4) {
    s0 += bf2f(xb[(size_t)(n + 0) * 128 + ch]);
    s1 += bf2f(xb[(size_t)(n + 1) * 128 + ch]);
    s2 += bf2f(xb[(size_t)(n + 2) * 128 + ch]);
    s3 += bf2f(xb[(size_t)(n + 3) * 128 + ch]);
  }
  for (; n < end; n++) s0 += bf2f(xb[(size_t)n * 128 + ch]);
  float s = (s0 + s1) + (s2 + s3);
  g[gid * 128 + ch] = s / fmaxf((float)(end - beg), 1.0f);
}

extern "C" void kernel_launch(void* const* d_in, const int* in_sizes, int n_in,
                              void* d_out, int out_size, void* d_ws, size_t ws_size,
                              hipStream_t stream) {
  const float* x   = (const float*)d_in[0];
  const int*   ei  = (const int*)d_in[1];
  const int*   cl  = (const int*)d_in[2];
  const float* Wl0 = (const float*)d_in[3];
  const float* bl0 = (const float*)d_in[4];
  const float* Wr0 = (const float*)d_in[5];
  const float* Wl1 = (const float*)d_in[6];
  const float* bl1 = (const float*)d_in[7];
  const float* Wr1 = (const float*)d_in[8];
  const float* Wl2 = (const float*)d_in[9];
  const float* bl2 = (const float*)d_in[10];
  const float* Wr2 = (const float*)d_in[11];
  float* out = (float*)d_out;

  char* ws = (char*)d_ws;
  u16*   xb0     = (u16*)  (ws);                  // 12,800,000 B (bf16 of x)
  u16*   xb1     = (u16*)  (ws + 12800000);       // 12,800,000 B (relu layer0)
  u16*   xb2     = (u16*)  (ws + 25600000);       // 12,800,000 B (relu layer1)
  u16*   aggb    = (u16*)  (ws + 38400000);       // 12,800,000 B
  u16*   WbT0    = (u16*)  (ws + 51200000);       //     65,536 B
  u16*   WbT1    = (u16*)  (ws + 51265536);       //     65,536 B
  u16*   WbT2    = (u16*)  (ws + 51331072);       //     32,768 B
  int*   deg     = (int*)  (ws + 51363840);       //    200,000 B
  int*   row_ptr = (int*)  (ws + 51564032);       //    200,004 B (+pad)
  int*   cursor  = (int*)  (ws + 51764736);       //    200,000 B
  int*   perm    = (int*)  (ws + 51964736);       //  2,400,000 B
  // total ~54.4 MB

  float* out_lsm = out;            // [50000,64]
  float* out_pre = out + 3200000;  // [50000,128]
  float* out_g   = out + 9600000;  // [512,128]

  // ---- CSR build (once) ----
  hipMemsetAsync(deg, 0, 200000, stream);
  deg_count_k<<<2344, 256, 0, stream>>>(ei, deg);
  scan_k<<<1, 1024, 0, stream>>>(deg, row_ptr, cursor);
  fill_k<<<2344, 256, 0, stream>>>(ei, cursor, perm);

  // ---- casts (x and weights) ----
  cast_k<<<12500, 256, 0, stream>>>(x, (u32*)xb0);
  castW_k<<<128, 256, 0, stream>>>(Wl0, Wr0, WbT0, 128);
  castW_k<<<128, 256, 0, stream>>>(Wl1, Wr1, WbT1, 128);
  castW_k<<<64, 256, 0, stream>>>(Wl2, Wr2, WbT2, 64);

  // ---- layer 0 ----
  gather_bf_k<<<12500, 256, 0, stream>>>(xb0, row_ptr, perm, aggb);
  sage128_mfma_k<false><<<6250, 256, 0, stream>>>(aggb, xb0, WbT0, bl0, xb1, nullptr);

  // ---- layer 1 (pre-relu f32 straight to d_out) ----
  gather_bf_k<<<12500, 256, 0, stream>>>(xb1, row_ptr, perm, aggb);
  sage128_mfma_k<true><<<6250, 256, 0, stream>>>(aggb, xb1, WbT1, bl1, xb2, out_pre);

  // ---- graph pooling of relu(layer1) ----
  pool_seg_k<<<NG, 128, 0, stream>>>(xb2, cl, out_g);

  // ---- final layer + log_softmax ----
  gather_bf_k<<<12500, 256, 0, stream>>>(xb2, row_ptr, perm, aggb);
  sage64_mfma_k<<<3125, 256, 0, stream>>>(aggb, xb2, WbT2, bl2, out_lsm);
}

// Round 11
// 415.176 us; speedup vs baseline: 4.9936x; 1.2368x over previous
//
#include <hip/hip_runtime.h>
#include <math.h>

#define NN 50000
#define NE 600000
#define NG 512

typedef unsigned int u32;
typedef unsigned short u16;

typedef __attribute__((ext_vector_type(8))) short bf16x8;
typedef __attribute__((ext_vector_type(4))) float f32x4;

__device__ __forceinline__ float bf2f(u16 u) {
  return __uint_as_float(((u32)u) << 16);
}
__device__ __forceinline__ u16 f2bf(float f) {
  u32 u = __float_as_uint(f);
  u32 lsb = (u >> 16) & 1u;
  u += 0x7fffu + lsb;          // RNE
  return (u16)(u >> 16);
}

// ================= CSR build (once per launch) ========
__global__ __launch_bounds__(256)
void deg_count_k(const int* __restrict__ ei, int* __restrict__ deg) {
  int e = blockIdx.x * 256 + threadIdx.x;
  if (e >= NE) return;
  atomicAdd(&deg[ei[NE + e]], 1);
}

// phase 1: per-block (256-wide) sums of deg -> bsum[196]
__global__ __launch_bounds__(256)
void scan1_k(const int* __restrict__ deg, int* __restrict__ bsum) {
  __shared__ int s[256];
  int idx = blockIdx.x * 256 + threadIdx.x;
  int v = (idx < NN) ? deg[idx] : 0;
  s[threadIdx.x] = v;
  __syncthreads();
  for (int off = 128; off > 0; off >>= 1) {
    if (threadIdx.x < off) s[threadIdx.x] += s[threadIdx.x + off];
    __syncthreads();
  }
  if (threadIdx.x == 0) bsum[blockIdx.x] = s[0];
}

// phase 2: single block scans the 196 block sums -> bofs (exclusive); row_ptr[NN] = NE
__global__ __launch_bounds__(256)
void scan2_k(const int* __restrict__ bsum, int* __restrict__ bofs, int* __restrict__ row_ptr) {
  __shared__ int s[256];
  int t = threadIdx.x;
  int v = (t < 196) ? bsum[t] : 0;
  s[t] = v;
  __syncthreads();
  for (int off = 1; off < 256; off <<= 1) {
    int add = (t >= off) ? s[t - off] : 0;
    __syncthreads();
    s[t] += add;
    __syncthreads();
  }
  if (t < 196) bofs[t] = s[t] - v;     // exclusive
  if (t == 0) row_ptr[NN] = NE;
}

// phase 3: per-block exclusive scan + block offset -> row_ptr, cursor
__global__ __launch_bounds__(256)
void scan3_k(const int* __restrict__ deg, const int* __restrict__ bofs,
             int* __restrict__ row_ptr, int* __restrict__ cursor) {
  __shared__ int s[256];
  int idx = blockIdx.x * 256 + threadIdx.x;
  int t = threadIdx.x;
  int v = (idx < NN) ? deg[idx] : 0;
  s[t] = v;
  __syncthreads();
  for (int off = 1; off < 256; off <<= 1) {
    int add = (t >= off) ? s[t - off] : 0;
    __syncthreads();
    s[t] += add;
    __syncthreads();
  }
  if (idx < NN) {
    int p = bofs[blockIdx.x] + s[t] - v;
    row_ptr[idx] = p;
    cursor[idx] = p;
  }
}

__global__ __launch_bounds__(256)
void fill_k(const int* __restrict__ ei, int* __restrict__ cursor, int* __restrict__ perm) {
  int e = blockIdx.x * 256 + threadIdx.x;
  if (e >= NE) return;
  int pos = atomicAdd(&cursor[ei[NE + e]], 1);
  perm[pos] = ei[e];
}

// ================= cast x (f32) -> xb (bf16) =================
__global__ __launch_bounds__(256)
void cast_k(const float* __restrict__ x, u32* __restrict__ xb) {
  int tid = blockIdx.x * 256 + threadIdx.x;       // 12500*256 = 3,200,000 exactly
  float2 v = ((const float2*)x)[tid];
  xb[tid] = (u32)f2bf(v.x) | ((u32)f2bf(v.y) << 16);
}

// ===== weight cast+transpose: WbT[n][k] = bf16( k<128 ? Wl[k][n] : Wr[k-128][n] ) =====
__global__ __launch_bounds__(256)
void castW_k(const float* __restrict__ Wl, const float* __restrict__ Wr,
             u16* __restrict__ WbT, int ncols) {   // ncols = 128 or 64
  int t = blockIdx.x * 256 + threadIdx.x;          // ncols*256 threads
  int n = t >> 8;
  int k = t & 255;
  if (n >= ncols) return;
  float v = (k < 128) ? Wl[k * ncols + n] : Wr[(k - 128) * ncols + n];
  WbT[n * 256 + k] = f2bf(v);
}

// ===== gather-mean (bf16 in, bf16 out): aggb[n] = bf16(mean_{e in(n)} xb[perm[e]]) =====
// one wave per node; lane owns channels (2*lane, 2*lane+1) = one u32.
// Batches of 16 independent row loads (index clamped, accumulate predicated):
// deg ~ Poisson(12) -> ~90% of nodes finish in ONE batch.
__global__ __launch_bounds__(256)
void gather_bf_k(const u16* __restrict__ xb, const int* __restrict__ row_ptr,
                 const int* __restrict__ perm, u16* __restrict__ aggb) {
  int wave = threadIdx.x >> 6;
  int lane = threadIdx.x & 63;
  int n = blockIdx.x * 4 + wave;          // 12500 * 4 = 50000
  int beg = row_ptr[n], end = row_ptr[n + 1];
  int cnt = end - beg;
  int co = lane * 2;
  float ax[8], ay[8];
#pragma unroll
  for (int j = 0; j < 8; j++) { ax[j] = 0.f; ay[j] = 0.f; }
  for (int base = 0; base < cnt; base += 16) {
    int rem = cnt - base;                 // wave-uniform, >0
    int last = rem - 1;
    int idx[16];
#pragma unroll
    for (int j = 0; j < 16; j++) idx[j] = perm[beg + base + min(j, last)];
    u32 u[16];
#pragma unroll
    for (int j = 0; j < 16; j++) u[j] = *(const u32*)(xb + (size_t)idx[j] * 128 + co);
#pragma unroll
    for (int j = 0; j < 16; j++) {
      bool live = j < rem;
      ax[j & 7] += live ? __uint_as_float(u[j] << 16) : 0.f;
      ay[j & 7] += live ? __uint_as_float(u[j] & 0xffff0000u) : 0.f;
    }
  }
  float sx = (ax[0]+ax[1])+(ax[2]+ax[3])+((ax[4]+ax[5])+(ax[6]+ax[7]));
  float sy = (ay[0]+ay[1])+(ay[2]+ay[3])+((ay[4]+ay[5])+(ay[6]+ay[7]));
  float inv = 1.0f / fmaxf((float)cnt, 1.0f);
  *(u32*)(aggb + (size_t)n * 128 + co) = (u32)f2bf(sx * inv) | ((u32)f2bf(sy * inv) << 16);
}

// ===== MFMA SAGE layer Cout=128: C = [aggb|xb] @ [Wl;Wr] (K=256, bf16, f32 acc) =====
// block 256 = 4 waves; wave = one 16x16 C tile; block = 16 rows x 64 cols.
// grid = 3125 row-tiles * 2 col-blocks = 6250. No LDS, no barriers.
template<bool WRITE_PRE>
__global__ __launch_bounds__(256)
void sage128_mfma_k(const u16* __restrict__ aggb, const u16* __restrict__ xbin,
                    const u16* __restrict__ WbT, const float* __restrict__ bl,
                    u16* __restrict__ xb_out, float* __restrict__ out_pre) {
  int wave = threadIdx.x >> 6;
  int lane = threadIdx.x & 63;
  int quad = lane >> 4;
  int m16  = lane & 15;
  int r0 = (blockIdx.x >> 1) * 16;
  int c0 = (blockIdx.x & 1) * 64 + wave * 16;

  const u16* arow_a = aggb + (size_t)(r0 + m16) * 128 + quad * 8;
  const u16* arow_x = xbin + (size_t)(r0 + m16) * 128 + quad * 8;
  const u16* brow   = WbT  + (size_t)(c0 + m16) * 256 + quad * 8;

  f32x4 acc = {0.f, 0.f, 0.f, 0.f};
#pragma unroll
  for (int ks = 0; ks < 8; ks++) {
    const u16* asrc = (ks < 4) ? arow_a : arow_x;
    bf16x8 a = *(const bf16x8*)(asrc + (ks & 3) * 32);
    bf16x8 b = *(const bf16x8*)(brow + ks * 32);
    acc = __builtin_amdgcn_mfma_f32_16x16x32_bf16(a, b, acc, 0, 0, 0);
  }
  int c = c0 + m16;
  float bv = bl[c];
#pragma unroll
  for (int r = 0; r < 4; r++) {
    int row = r0 + quad * 4 + r;
    float v = acc[r] + bv;
    if (WRITE_PRE) out_pre[(size_t)row * 128 + c] = v;
    xb_out[(size_t)row * 128 + c] = f2bf(fmaxf(v, 0.f));
  }
}

// ===== MFMA final layer Cout=64 + fused log_softmax =====
__global__ __launch_bounds__(256)
void sage64_mfma_k(const u16* __restrict__ aggb, const u16* __restrict__ xbin,
                   const u16* __restrict__ WbT, const float* __restrict__ bl,
                   float* __restrict__ out) {
  __shared__ float sC[16][64];
  int wave = threadIdx.x >> 6;
  int lane = threadIdx.x & 63;
  int quad = lane >> 4;
  int m16  = lane & 15;
  int r0 = blockIdx.x * 16;
  int c0 = wave * 16;

  const u16* arow_a = aggb + (size_t)(r0 + m16) * 128 + quad * 8;
  const u16* arow_x = xbin + (size_t)(r0 + m16) * 128 + quad * 8;
  const u16* brow   = WbT  + (size_t)(c0 + m16) * 256 + quad * 8;

  f32x4 acc = {0.f, 0.f, 0.f, 0.f};
#pragma unroll
  for (int ks = 0; ks < 8; ks++) {
    const u16* asrc = (ks < 4) ? arow_a : arow_x;
    bf16x8 a = *(const bf16x8*)(asrc + (ks & 3) * 32);
    bf16x8 b = *(const bf16x8*)(brow + ks * 32);
    acc = __builtin_amdgcn_mfma_f32_16x16x32_bf16(a, b, acc, 0, 0, 0);
  }
  int c = c0 + m16;
  float bv = bl[c];
#pragma unroll
  for (int r = 0; r < 4; r++) sC[quad * 4 + r][c] = acc[r] + bv;
  __syncthreads();
  if (threadIdx.x < 16) {
    int r = threadIdx.x;
    float m = -1e30f;
    for (int j = 0; j < 64; j++) m = fmaxf(m, sC[r][j]);
    float s = 0.f;
    for (int j = 0; j < 64; j++) s += __expf(sC[r][j] - m);
    float ls = __logf(s);
    float* orow = out + (size_t)(r0 + r) * 64;
    for (int j = 0; j < 64; j++) orow[j] = sC[r][j] - m - ls;
  }
}

// ======= graph pooling from bf16 (cluster sorted -> segmented mean, no atomics) =======
__global__ __launch_bounds__(128)
void pool_seg_k(const u16* __restrict__ xb, const int* __restrict__ cluster,
                float* __restrict__ g) {
  int gid = blockIdx.x;          // 512
  int ch = threadIdx.x;          // 128
  int lo = 0, hi = NN;
  while (lo < hi) { int mid = (lo + hi) >> 1; if (cluster[mid] < gid) lo = mid + 1; else hi = mid; }
  int beg = lo;
  hi = NN;
  while (lo < hi) { int mid = (lo + hi) >> 1; if (cluster[mid] < gid + 1) lo = mid + 1; else hi = mid; }
  int end = lo;
  float s0 = 0.f, s1 = 0.f, s2 = 0.f, s3 = 0.f;
  int n = beg;
  for (; n + 4 <= end; n += 4) {
    s0 += bf2f(xb[(size_t)(n + 0) * 128 + ch]);
    s1 += bf2f(xb[(size_t)(n + 1) * 128 + ch]);
    s2 += bf2f(xb[(size_t)(n + 2) * 128 + ch]);
    s3 += bf2f(xb[(size_t)(n + 3) * 128 + ch]);
  }
  for (; n < end; n++) s0 += bf2f(xb[(size_t)n * 128 + ch]);
  float s = (s0 + s1) + (s2 + s3);
  g[gid * 128 + ch] = s / fmaxf((float)(end - beg), 1.0f);
}

extern "C" void kernel_launch(void* const* d_in, const int* in_sizes, int n_in,
                              void* d_out, int out_size, void* d_ws, size_t ws_size,
                              hipStream_t stream) {
  const float* x   = (const float*)d_in[0];
  const int*   ei  = (const int*)d_in[1];
  const int*   cl  = (const int*)d_in[2];
  const float* Wl0 = (const float*)d_in[3];
  const float* bl0 = (const float*)d_in[4];
  const float* Wr0 = (const float*)d_in[5];
  const float* Wl1 = (const float*)d_in[6];
  const float* bl1 = (const float*)d_in[7];
  const float* Wr1 = (const float*)d_in[8];
  const float* Wl2 = (const float*)d_in[9];
  const float* bl2 = (const float*)d_in[10];
  const float* Wr2 = (const float*)d_in[11];
  float* out = (float*)d_out;

  char* ws = (char*)d_ws;
  u16*   xb0     = (u16*)  (ws);                  // 12,800,000 B (bf16 of x)
  u16*   xb1     = (u16*)  (ws + 12800000);       // 12,800,000 B (relu layer0)
  u16*   xb2     = (u16*)  (ws + 25600000);       // 12,800,000 B (relu layer1)
  u16*   aggb    = (u16*)  (ws + 38400000);       // 12,800,000 B
  u16*   WbT0    = (u16*)  (ws + 51200000);       //     65,536 B
  u16*   WbT1    = (u16*)  (ws + 51265536);       //     65,536 B
  u16*   WbT2    = (u16*)  (ws + 51331072);       //     32,768 B
  int*   deg     = (int*)  (ws + 51363840);       //    200,000 B
  int*   row_ptr = (int*)  (ws + 51564032);       //    200,004 B (+pad)
  int*   cursor  = (int*)  (ws + 51764736);       //    200,000 B
  int*   perm    = (int*)  (ws + 51964736);       //  2,400,000 B
  int*   bsum    = (int*)  (ws + 54364736);       //        784 B
  int*   bofs    = (int*)  (ws + 54365568);       //        784 B
  // total ~54.4 MB

  float* out_lsm = out;            // [50000,64]
  float* out_pre = out + 3200000;  // [50000,128]
  float* out_g   = out + 9600000;  // [512,128]

  // ---- CSR build (once): deg -> 3-phase parallel scan -> fill ----
  hipMemsetAsync(deg, 0, 200000, stream);
  deg_count_k<<<2344, 256, 0, stream>>>(ei, deg);
  scan1_k<<<196, 256, 0, stream>>>(deg, bsum);
  scan2_k<<<1, 256, 0, stream>>>(bsum, bofs, row_ptr);
  scan3_k<<<196, 256, 0, stream>>>(deg, bofs, row_ptr, cursor);
  fill_k<<<2344, 256, 0, stream>>>(ei, cursor, perm);

  // ---- casts (x and weights) ----
  cast_k<<<12500, 256, 0, stream>>>(x, (u32*)xb0);
  castW_k<<<128, 256, 0, stream>>>(Wl0, Wr0, WbT0, 128);
  castW_k<<<128, 256, 0, stream>>>(Wl1, Wr1, WbT1, 128);
  castW_k<<<64, 256, 0, stream>>>(Wl2, Wr2, WbT2, 64);

  // ---- layer 0 ----
  gather_bf_k<<<12500, 256, 0, stream>>>(xb0, row_ptr, perm, aggb);
  sage128_mfma_k<false><<<6250, 256, 0, stream>>>(aggb, xb0, WbT0, bl0, xb1, nullptr);

  // ---- layer 1 (pre-relu f32 straight to d_out) ----
  gather_bf_k<<<12500, 256, 0, stream>>>(xb1, row_ptr, perm, aggb);
  sage128_mfma_k<true><<<6250, 256, 0, stream>>>(aggb, xb1, WbT1, bl1, xb2, out_pre);

  // ---- graph pooling of relu(layer1) ----
  pool_seg_k<<<NG, 128, 0, stream>>>(xb2, cl, out_g);

  // ---- final layer + log_softmax ----
  gather_bf_k<<<12500, 256, 0, stream>>>(xb2, row_ptr, perm, aggb);
  sage64_mfma_k<<<3125, 256, 0, stream>>>(aggb, xb2, WbT2, bl2, out_lsm);
}